// Round 1
// baseline (86.241 us; speedup 1.0000x reference)
//
#include <hip/hip_runtime.h>

// Multinomial sampling via sum tree (prioritized-replay style).
// CAP = 2^21 leaves, NSAMP = 2^20 stratified samples, depth = 21.
// Tree layout (matches reference): levels concatenated root-first;
// level k (2^k nodes) starts at offset 2^k - 1; children of i at 2i+1, 2i+2.
// We store ONLY internal nodes (2^21 - 1 floats, ~8 MB) in d_ws; the leaf
// level is read directly from the priorities input.

#define CAP   2097152   // 2^21
#define NSAMP 1048576   // 2^20

// ---- Stage A: internal levels 20..9 -------------------------------------
// 512 blocks x 256 threads; each block owns 4096 contiguous leaves and
// reduces them through LDS ping-pong, writing each level coalesced.
__global__ __launch_bounds__(256) void build_lower(const float* __restrict__ prio,
                                                   float* __restrict__ tree) {
    __shared__ float bufA[2048];
    __shared__ float bufB[1024];
    const int b = blockIdx.x;
    const int t = threadIdx.x;

    // Level 20 (2^20 nodes at offset 2^20-1): pairwise sums of leaves.
    const float4* p4 = (const float4*)(prio + (size_t)b * 4096);
    #pragma unroll
    for (int q = 0; q < 4; ++q) {
        float4 a = p4[t * 4 + q];
        bufA[t * 8 + q * 2 + 0] = a.x + a.y;
        bufA[t * 8 + q * 2 + 1] = a.z + a.w;
    }
    __syncthreads();
    {
        float* g = tree + ((1 << 20) - 1) + b * 2048;
        #pragma unroll
        for (int i = t; i < 2048; i += 256) g[i] = bufA[i];   // coalesced
    }

    // Levels 19..9 via LDS ping-pong (exact pairwise sums, same as reference).
    float* src = bufA;
    float* dst = bufB;
    int cnt = 1024;              // nodes this block produces at current level
    int off = (1 << 19) - 1;     // global offset of current level
    for (int lvl = 19; lvl >= 9; --lvl) {
        for (int i = t; i < cnt; i += 256) {
            float2 v = ((const float2*)src)[i];
            float r = v.x + v.y;
            dst[i] = r;
            tree[off + b * cnt + i] = r;
        }
        __syncthreads();
        float* tmp = src; src = dst; dst = tmp;
        off = (off - 1) >> 1;    // 2^k-1 -> 2^(k-1)-1
        cnt >>= 1;
    }
}

// ---- Stage B: levels 8..0 (single block) --------------------------------
__global__ __launch_bounds__(256) void build_upper(float* __restrict__ tree) {
    __shared__ float bufA[512];
    __shared__ float bufB[256];
    const int t = threadIdx.x;
    bufA[t]       = tree[511 + t];        // level 9: 512 nodes at offset 511
    bufA[t + 256] = tree[511 + t + 256];
    __syncthreads();
    float* src = bufA;
    float* dst = bufB;
    int cnt = 256;
    int off = 255;
    for (int lvl = 8; lvl >= 0; --lvl) {
        for (int i = t; i < cnt; i += 256) {
            float2 v = ((const float2*)src)[i];
            float r = v.x + v.y;
            dst[i] = r;
            tree[off + i] = r;
        }
        __syncthreads();
        float* tmp = src; src = dst; dst = tmp;
        off = (off - 1) >> 1;
        cnt >>= 1;
    }
}

// ---- Stage C: stratified sampling traversal -----------------------------
__global__ __launch_bounds__(256) void sample_kernel(const float* __restrict__ tree,
                                                     const float* __restrict__ prio,
                                                     const float* __restrict__ uniform,
                                                     int* __restrict__ out) {
    const int j = blockIdx.x * 256 + threadIdx.x;
    const float total = tree[0];
    const float scale = total / (float)NSAMP;            // exact (pow-2 divide)
    float s = uniform[j] * total / (float)NSAMP + scale * (float)j;

    int idx = 0;
    #pragma unroll
    for (int d = 0; d < 20; ++d) {       // internal levels
        int left = 2 * idx + 1;
        float lv = tree[left];
        bool right = (s > lv);            // reference: go_left = (s <= left_val)
        s = right ? (s - lv) : s;
        idx = right ? (left + 1) : left;
    }
    // Final level: children are leaves; read from priorities directly.
    int left = 2 * idx + 1;               // in [2^21-1, 2^22-3]
    float lv = prio[left - (CAP - 1)];
    idx = (s > lv) ? (left + 1) : left;
    out[j] = idx - (CAP - 1);             // leaf index in [0, CAP)
}

extern "C" void kernel_launch(void* const* d_in, const int* in_sizes, int n_in,
                              void* d_out, int out_size, void* d_ws, size_t ws_size,
                              hipStream_t stream) {
    const float* prio    = (const float*)d_in[0];  // [CAP]
    const float* uniform = (const float*)d_in[1];  // [NSAMP]
    (void)in_sizes; (void)n_in; (void)out_size; (void)ws_size;

    float* tree = (float*)d_ws;   // (CAP - 1) floats = internal nodes

    build_lower<<<512, 256, 0, stream>>>(prio, tree);
    build_upper<<<1, 256, 0, stream>>>(tree);
    sample_kernel<<<NSAMP / 256, 256, 0, stream>>>(tree, prio, uniform, (int*)d_out);
}

// Round 2
// 76.082 us; speedup vs baseline: 1.1335x; 1.1335x over previous
//
#include <hip/hip_runtime.h>

// Multinomial via sum tree. CAP=2^21 leaves, NSAMP=2^20 stratified samples.
// Tree stored in ws holds ONLY internal levels 9..18 (slots 511..524286 of the
// standard root-first layout; 2^19-1 floats total = 2 MB). Levels 19,20 + leaf
// comparisons are computed in-register from an 8-leaf (32 B) prio load.
// Levels 0..8 are rebuilt per-block in LDS (exact pairwise sums -> identical
// values in every block, bit-identical to the reference tree).

#define CAP    (1 << 21)
#define NSAMP  (1 << 20)
#define L18OFF ((1 << 18) - 1)   // 262143: offset of level 18

// ---- Build internal levels 18..9 ----------------------------------------
// 512 blocks x 256 threads; block owns 4096 leaves -> 512 level-18 nodes.
__global__ __launch_bounds__(256) void build_tree(const float* __restrict__ prio,
                                                  float* __restrict__ tree) {
    __shared__ __align__(16) float A[512];
    __shared__ __align__(16) float B[256];
    const int b = blockIdx.x, t = threadIdx.x;
    const float4* p4 = (const float4*)(prio + (size_t)b * 4096);

    // level 18: each node = sum of 8 leaves, reference association.
    #pragma unroll
    for (int i = t; i < 512; i += 256) {
        float4 x = p4[2 * i], y = p4[2 * i + 1];
        A[i] = ((x.x + x.y) + (x.z + x.w)) + ((y.x + y.y) + (y.z + y.w));
    }
    __syncthreads();
    {
        float* g = tree + L18OFF + b * 512;
        #pragma unroll
        for (int i = t; i < 512; i += 256) g[i] = A[i];   // coalesced
    }
    // levels 17..9 via LDS ping-pong (exact pairwise sums).
    float* src = A;
    float* dst = B;
    int cnt = 256;                 // nodes this block produces at current level
    int off = (1 << 17) - 1;
    for (int lvl = 17; lvl >= 9; --lvl) {
        for (int i = t; i < cnt; i += 256) {
            float2 v = ((const float2*)src)[i];
            float r = v.x + v.y;
            dst[i] = r;
            tree[off + b * cnt + i] = r;
        }
        __syncthreads();
        float* tmp = src; src = dst; dst = tmp;
        off = (off - 1) >> 1;
        cnt >>= 1;
    }
}

// ---- Sample: 1024 blocks x 256 threads x 4 samples/thread ---------------
__global__ __launch_bounds__(256) void sample_kernel(const float* __restrict__ tree,
                                                     const float* __restrict__ prio,
                                                     const float* __restrict__ uniform,
                                                     int* __restrict__ out) {
    __shared__ float nds[8191];          // nodes 0..8190 = levels 0..12 (32 KB)
    const int t = threadIdx.x;

    // stage levels 9..12 (slots 511..8190) from the built tree, coalesced
    for (int i = 511 + t; i < 8191; i += 256) nds[i] = tree[i];
    __syncthreads();
    // rebuild levels 8..0 in LDS (identical in every block; exact sums)
    {
        int cnt = 256, off = 255;
        for (int lvl = 8; lvl >= 0; --lvl) {
            for (int i = t; i < cnt; i += 256) {
                int n = off + i;
                nds[n] = nds[2 * n + 1] + nds[2 * n + 2];
            }
            __syncthreads();
            off = (off - 1) >> 1;
            cnt >>= 1;
        }
    }

    const float total = nds[0];
    const float scale = total / (float)NSAMP;     // exact pow-2 divide
    const int base = blockIdx.x * 1024 + t;

    float s[4];
    int   id[4];
    #pragma unroll
    for (int q = 0; q < 4; ++q) {
        int j = base + 256 * q;
        s[q]  = uniform[j] * total / (float)NSAMP + scale * (float)j;  // == ref
        id[q] = 0;
    }

    // steps 0..11: levels 1..12 from LDS (4 independent chains -> ILP)
    #pragma unroll
    for (int d = 0; d < 12; ++d) {
        #pragma unroll
        for (int q = 0; q < 4; ++q) {
            int left = 2 * id[q] + 1;
            float lv = nds[left];
            bool r = s[q] > lv;                   // ref: go_left = s <= lv
            s[q]  = r ? s[q] - lv : s[q];
            id[q] = r ? left + 1 : left;
        }
    }
    // steps 12..17: levels 13..18 from global (L1/L2-resident windows)
    #pragma unroll
    for (int d = 0; d < 6; ++d) {
        #pragma unroll
        for (int q = 0; q < 4; ++q) {
            int left = 2 * id[q] + 1;
            float lv = tree[left];
            bool r = s[q] > lv;
            s[q]  = r ? s[q] - lv : s[q];
            id[q] = r ? left + 1 : left;
        }
    }
    // bottom 3 levels from one 32 B leaf load, all in registers
    #pragma unroll
    for (int q = 0; q < 4; ++q) {
        int p = id[q] - L18OFF;                       // level-18 position
        const float4* pp = (const float4*)prio + 2 * (size_t)p;
        float4 x = pp[0], y = pp[1];                  // leaves 8p..8p+7
        float l19 = (x.x + x.y) + (x.z + x.w);        // level-19 left child
        bool r1 = s[q] > l19;
        float ss = r1 ? s[q] - l19 : s[q];
        float l20 = r1 ? (y.x + y.y) : (x.x + x.y);   // level-20 left child
        bool r2 = ss > l20;
        ss = r2 ? ss - l20 : ss;
        float leaf = r1 ? (r2 ? y.z : y.x) : (r2 ? x.z : x.x);  // left leaf
        bool r3 = ss > leaf;
        out[base + 256 * q] = 8 * p + (r1 ? 4 : 0) + (r2 ? 2 : 0) + (r3 ? 1 : 0);
    }
}

extern "C" void kernel_launch(void* const* d_in, const int* in_sizes, int n_in,
                              void* d_out, int out_size, void* d_ws, size_t ws_size,
                              hipStream_t stream) {
    const float* prio    = (const float*)d_in[0];   // [CAP]
    const float* uniform = (const float*)d_in[1];   // [NSAMP]
    (void)in_sizes; (void)n_in; (void)out_size; (void)ws_size;

    float* tree = (float*)d_ws;    // 2^19-1 floats; slots 511..524286 used

    build_tree<<<512, 256, 0, stream>>>(prio, tree);
    sample_kernel<<<NSAMP / 1024, 256, 0, stream>>>(tree, prio, uniform, (int*)d_out);
}